// Round 26
// baseline (84.722 us; speedup 1.0000x reference)
//
#include <hip/hip_runtime.h>
#include <math.h>

// B=256, P=40, S=60, D=64. Round-26 = Round-25 body + SEQUENTIAL 2-part
// rolled loop. Model: R20/R25 (10240 one-part waves, 512-thr) are wave-
// dispatch-limited at ~146 waves/us (both walls = #waves/146). Halving wave
// count (640 WGs x 8 waves x 2 parts) drops the dispatch floor to ~35 us;
// the sequential chain (2 x 10.6 us) stays under it. R21's failure was
// INTERLEAVING both parts' registers (allocator serialize-to-fit at 128);
// here iterations are strictly sequential, reusing the same LDS x-tile and
// the same register set (liveness = R25's ~116). sched_barrier(0) pins the
// back-edge against load hoisting (R14-verified).
//
// Register-chain trick: MFMA contraction is invariant to permuting the k-dim.
// C/D output holds the row-dim in-lane as {16mt+4g+j}; the next GEMM
// contracting that dim takes both operands by pure register reindexing:
//     frag[nt][ks] = pk16( acc2[2ks][nb], acc2[2ks+1][nb] )
// map pi(ks,i,g)=16*(2ks+(i>>2))+4g+(i&3). W1/W2 pre-permuted to pi-layout.
//
// Layout facts (cdna4 guide, measured m89/m91):
//   C/D: lane holds col=lane&15, rows 16mt+4(lane>>4)+j
//   A/B: row(col)=lane&15, kappa = 32ks+8(lane>>4)+i

typedef _Float16 half8 __attribute__((ext_vector_type(8)));
typedef __fp16 fp16x2 __attribute__((ext_vector_type(2)));
typedef float f4 __attribute__((ext_vector_type(4)));

#define MFMA16(a, b, c) __builtin_amdgcn_mfma_f32_16x16x32_f16((a), (b), (c), 0, 0, 0)

__global__ __launch_bounds__(256) void prep_weights(
    const float* __restrict__ Wq, const float* __restrict__ Wk,
    const float* __restrict__ Wv, const float* __restrict__ W1,
    const float* __restrict__ W2, _Float16* __restrict__ wsH) {
    int idx = blockIdx.x * 256 + threadIdx.x;  // 0..20479
    int m = idx >> 12, r = idx & 4095;
    const float* src = (m == 0) ? Wq : (m == 1) ? Wk : (m == 2) ? Wv
                        : (m == 3) ? W1 : W2;
    float v;
    if (m < 3) {
        v = src[r];  // natural row-major [e][d]
    } else {
        // pi-permuted: position (e, kappa) holds W[e][ d=16*(2ks+(i>>2))+4g+(i&3) ]
        int e = r >> 6, kp = r & 63;
        int ks = kp >> 5, gg = (kp >> 3) & 3, i = kp & 7;
        int d = 16 * (2 * ks + (i >> 2)) + 4 * gg + (i & 3);
        v = src[e * 64 + d];
    }
    wsH[idx] = (_Float16)v;
}

// Packed f32x4 + f32x4 -> half8 via v_cvt_pkrtz_f16_f32 (4 insts).
__device__ __forceinline__ half8 pk8(f4 a, f4 b) {
    union { half8 h; fp16x2 p[4]; } u;
    u.p[0] = __builtin_amdgcn_cvt_pkrtz(a[0], a[1]);
    u.p[1] = __builtin_amdgcn_cvt_pkrtz(a[2], a[3]);
    u.p[2] = __builtin_amdgcn_cvt_pkrtz(b[0], b[1]);
    u.p[3] = __builtin_amdgcn_cvt_pkrtz(b[2], b[3]);
    return u.h;
}

// acc2 -> pi-layout frags for this half (dst[2h+nb][ks]).
#define MKFR_H(dst, RELU)                                                    \
    do {                                                                     \
        _Pragma("unroll")                                                    \
        for (int nb = 0; nb < 2; ++nb)                                       \
            _Pragma("unroll")                                                \
            for (int ks = 0; ks < 2; ++ks) {                                 \
                f4 a_ = acc2[2 * ks][nb], b_ = acc2[2 * ks + 1][nb];         \
                if (RELU) {                                                  \
                    _Pragma("unroll")                                        \
                    for (int j = 0; j < 4; ++j) {                            \
                        a_[j] = fmaxf(a_[j], 0.f);                           \
                        b_[j] = fmaxf(b_[j], 0.f);                           \
                    }                                                        \
                }                                                            \
                dst[2 * h + nb][ks] = pk8(a_, b_);                           \
            }                                                                \
    } while (0)

// Half-width GEMM into acc2[4][2] with A already in regs (AREG indexed
// [mt][ks]); B loaded per (h, ks). Used for scores/PV (A = kf/vf).
#define GEMM_R(AREG, BEXPR, CEXPR)                                           \
    do {                                                                     \
        _Pragma("unroll")                                                    \
        for (int ks = 0; ks < 2; ++ks) {                                     \
            half8 bfr[2];                                                    \
            _Pragma("unroll")                                                \
            for (int nb = 0; nb < 2; ++nb) {                                 \
                const int nt = 2 * h + nb; (void)nt;                         \
                bfr[nb] = (BEXPR);                                           \
            }                                                                \
            _Pragma("unroll")                                                \
            for (int mt = 0; mt < 4; ++mt)                                   \
                _Pragma("unroll")                                            \
                for (int nb = 0; nb < 2; ++nb) {                             \
                    const int nt = 2 * h + nb; (void)nt;                     \
                    acc2[mt][nb] = MFMA16(AREG[mt][ks], bfr[nb],             \
                                          ks == 0 ? (CEXPR) : acc2[mt][nb]); \
                }                                                            \
        }                                                                    \
    } while (0)

// Full stage with A-frag preload shared across BOTH halves.
// AEXPR uses (t, ks); BEXPR uses (nt, ks); CEXPR uses (mt, nb, nt).
#define STAGE_A(AEXPR, BEXPR, CEXPR, DST, RELU)                              \
    do {                                                                     \
        half8 afr2[4][2];                                                    \
        _Pragma("unroll")                                                    \
        for (int t = 0; t < 4; ++t)                                          \
            _Pragma("unroll")                                                \
            for (int ks = 0; ks < 2; ++ks) afr2[t][ks] = (AEXPR);            \
        _Pragma("unroll")                                                    \
        for (int h = 0; h < 2; ++h) {                                        \
            GEMM_R(afr2, BEXPR, CEXPR);                                      \
            MKFR_H(DST, RELU);                                               \
        }                                                                    \
    } while (0)

// Weight fragment from LDS: matrix widx, row-block RB (row = 16*RB+lo),
// kappa chunk (32ks+8g), XOR-swizzled by (lo&7)<<3 halves.
#define WFRAG(widx, RB) (*(const half8*)&wlds[(widx) * 4096 + (16 * (RB) + lo) * 64 + \
                                              ((32 * ks + 8 * g) ^ ((lo & 7) << 3))])

// x fragment from LDS (rows >= 60 -> zero; constant-folds for RB < 3).
#define XFRAG(RB) __extension__({                                            \
    int row_ = 16 * (RB) + lo;                                               \
    int rowc_ = row_ < 60 ? row_ : 48;                                       \
    half8 v_ = *(const half8*)&wlds[xbase + rowc_ * 64 +                     \
                                    ((32 * ks + 8 * g) ^ ((lo & 7) << 3))];  \
    if (row_ >= 60) { half8 z_ = {}; v_ = z_; }                              \
    v_; })

__global__ __launch_bounds__(512, 1) void fused_f16(
    const float* __restrict__ x, const _Float16* __restrict__ wH,
    const float* __restrict__ bq, const float* __restrict__ bk,
    const float* __restrict__ bv, const float* __restrict__ b1,
    const float* __restrict__ b2, const float* __restrict__ W3,
    const float* __restrict__ b3, float* __restrict__ out) {
    // 40 KB weights + 8 x-tiles (60x64 f16, swizzled) = 102400 B = 100 KB.
    __shared__ __align__(16) _Float16 wlds[51200];

    const int tid = threadIdx.x;
    const int l = tid & 63;           // lane
    const int w = tid >> 6;           // wave 0..7 (TWO sequential parts each)
    const int lo = l & 15, g = l >> 4;

    // ---- cooperative weight load global->LDS with write-side swizzle.
    #pragma unroll
    for (int rep = 0; rep < 5; ++rep) {
        int chunk = rep * 512 + tid;          // 0..2559
        int widx = chunk >> 9;
        int rem = chunk & 511;
        int row = rem >> 3, c = rem & 7;
        *(half8*)&wlds[widx * 4096 + row * 64 + ((c * 8) ^ ((row & 7) << 3))] =
            *(const half8*)&wH[widx * 4096 + row * 64 + c * 8];
    }
    __syncthreads();  // weights visible to all; waves independent afterwards

    const int part0 = blockIdx.x * 16 + w * 2;  // two consecutive parts
    const int xbase = 20480 + w * 3840;         // x tile reused per iteration

    #pragma unroll 1
    for (int it = 0; it < 2; ++it) {
        // Pin the back-edge: iteration it+1's loads may not hoist into it.
        __builtin_amdgcn_sched_barrier(0);

        const int part = part0 + it;
        const float* __restrict__ xp = x + (size_t)part * (60 * 64);

        // ---- stage this part's x into LDS (f16, swizzled). Same-wave
        // in-order LDS: this iteration's writes follow prior reads.
        #pragma unroll
        for (int m = 0; m < 8; ++m) {
            int chunk = m * 64 + l;           // 480 16B-chunks (60 rows x 8)
            if (chunk < 480) {
                int row = chunk >> 3, c = chunk & 7;
                const float* p = xp + row * 64 + c * 8;
                half8 hv = pk8(*(const f4*)p, *(const f4*)(p + 4));
                *(half8*)&wlds[xbase + row * 64 + ((c * 8) ^ ((row & 7) << 3))] = hv;
            }
        }

        const f4 zc = {0.f, 0.f, 0.f, 0.f};
        f4 acc2[4][2];
        f4 brow[4];
        half8 qf[4][2], kf[4][2], vf[4][2], pf[4][2], wtf[4][2], h1f[4][2];

        // ---- qT = Wq * xT + bq   (A = Wq preloaded, shared across halves)
        #pragma unroll
        for (int mt = 0; mt < 4; ++mt) brow[mt] = *(const f4*)&bq[16 * mt + 4 * g];
        STAGE_A(WFRAG(0, t), XFRAG(nt), brow[mt], qf, false);

        // ---- kT = Wk * xT + bk
        #pragma unroll
        for (int mt = 0; mt < 4; ++mt) brow[mt] = *(const f4*)&bk[16 * mt + 4 * g];
        STAGE_A(WFRAG(1, t), XFRAG(nt), brow[mt], kf, false);

        // ---- scoresT + softmax + P, per half (A = kf regs, B = qf regs)
        #pragma unroll
        for (int h = 0; h < 2; ++h) {
            GEMM_R(kf, qf[nt][ks], zc);
            #pragma unroll
            for (int nb = 0; nb < 2; ++nb) {
                float sum = 0.f;
                #pragma unroll
                for (int mt = 0; mt < 4; ++mt)
                    #pragma unroll
                    for (int j = 0; j < 4; ++j) {
                        float e = (mt == 3 && g == 3)
                                      ? 0.f
                                      : exp2f(acc2[mt][nb][j] *
                                              0.1803368801111137f);
                        acc2[mt][nb][j] = e;
                        sum += e;
                    }
                sum += __shfl_xor(sum, 16);
                sum += __shfl_xor(sum, 32);
                float inv = 1.f / sum;
                #pragma unroll
                for (int mt = 0; mt < 4; ++mt)
                    #pragma unroll
                    for (int j = 0; j < 4; ++j) acc2[mt][nb][j] *= inv;
            }
            MKFR_H(pf, false);
        }
        // qf, kf dead here.

        // ---- v = x * WvT + bv   (A = x preloaded once, shared across halves)
        {
            float bcol[4];
            #pragma unroll
            for (int nt = 0; nt < 4; ++nt) bcol[nt] = bv[16 * nt + lo];
            STAGE_A(XFRAG(t), WFRAG(2, nt),
                    ((f4){bcol[nt], bcol[nt], bcol[nt], bcol[nt]}), vf, false);
        }

        // ---- weightedT = vT * P, per half (A = vf regs, B = pf regs)
        #pragma unroll
        for (int h = 0; h < 2; ++h) {
            GEMM_R(vf, pf[nt][ks], zc);
            MKFR_H(wtf, false);
        }
        // vf, pf dead here.

        // ---- h1T = relu(W1 * weightedT + b1)   (W1 pi-permuted, A preloaded)
        #pragma unroll
        for (int mt = 0; mt < 4; ++mt) brow[mt] = *(const f4*)&b1[16 * mt + 4 * g];
        STAGE_A(WFRAG(3, t), wtf[nt][ks], brow[mt], h1f, true);

        // ---- h2T = relu(W2 * h1T + b2), head folded per half on f32 acc
        #pragma unroll
        for (int mt = 0; mt < 4; ++mt) brow[mt] = *(const f4*)&b2[16 * mt + 4 * g];
        f4 w3r[4];
        #pragma unroll
        for (int mt = 0; mt < 4; ++mt) w3r[mt] = *(const f4*)&W3[16 * mt + 4 * g];
        float b3v = b3[0];
        {
            half8 afr2[4][2];
            #pragma unroll
            for (int t = 0; t < 4; ++t)
                #pragma unroll
                for (int ks = 0; ks < 2; ++ks) afr2[t][ks] = WFRAG(4, t);
            #pragma unroll
            for (int h = 0; h < 2; ++h) {
                GEMM_R(afr2, h1f[nt][ks], brow[mt]);
                #pragma unroll
                for (int nb = 0; nb < 2; ++nb) {
                    float sres = 0.f;
                    #pragma unroll
                    for (int mt = 0; mt < 4; ++mt)
                        #pragma unroll
                        for (int j = 0; j < 4; ++j)
                            sres += fmaxf(acc2[mt][nb][j], 0.f) * w3r[mt][j];
                    sres += __shfl_xor(sres, 16);
                    sres += __shfl_xor(sres, 32);
                    if (g == 0) {
                        int s = 16 * (2 * h + nb) + lo;
                        if (s < 60) out[(size_t)part * 60 + s] = sres + b3v;
                    }
                }
            }
        }
    }
}

extern "C" void kernel_launch(void* const* d_in, const int* in_sizes, int n_in,
                              void* d_out, int out_size, void* d_ws, size_t ws_size,
                              hipStream_t stream) {
    const float* x  = (const float*)d_in[0];
    const float* Wq = (const float*)d_in[1];
    const float* bq = (const float*)d_in[2];
    const float* Wk = (const float*)d_in[3];
    const float* bk = (const float*)d_in[4];
    const float* Wv = (const float*)d_in[5];
    const float* bv = (const float*)d_in[6];
    const float* W1 = (const float*)d_in[7];
    const float* b1 = (const float*)d_in[8];
    const float* W2 = (const float*)d_in[9];
    const float* b2 = (const float*)d_in[10];
    const float* W3 = (const float*)d_in[11];
    const float* b3 = (const float*)d_in[12];
    _Float16* wsH = (_Float16*)d_ws;  // 5 * 4096 halves = 40 KB

    prep_weights<<<80, 256, 0, stream>>>(Wq, Wk, Wv, W1, W2, wsH);
    // 640 WGs x 512 thr = 5120 waves; each wave runs 2 sequential parts.
    // Dispatch floor ~5120/146 = 35 us; chain 2 x ~10.6 us per wave.
    fused_f16<<<640, 512, 0, stream>>>(x, wsH, bq, bk, bv, b1, b2, W3, b3,
                                       (float*)d_out);
}

// Round 27
// 81.591 us; speedup vs baseline: 1.0384x; 1.0384x over previous
//
#include <hip/hip_runtime.h>
#include <math.h>

// B=256, P=40, S=60, D=64. Round-27 = Round-26 minus the A-frag preload.
// R26 post-mortem: the 2-part loop spilled (VGPR 128 + 18 MB scratch)
// because R25's STAGE_A preload (+32 transient regs) + loop state exceeded
// the 512-thr 128-reg budget. The preload was a NULL optimization anyway
// (R25 = R20 = 69.5/69.9 us). Body returns to R20's per-half A-load form
// (112 VGPR standalone; ~124 in-loop -> fits 128, no spill).
// Keep: 640 WGs x 512 thr, 2 sequential parts/wave (5120 waves vs 10240 --
// R20/R25 are wave-dispatch-limited at ~146 waves/us), same LDS x-tile
// reused per iteration, sched_barrier(0) back-edge pin (R14).
//
// Register-chain trick: MFMA contraction is invariant to permuting the k-dim.
// C/D output holds the row-dim in-lane as {16mt+4g+j}; the next GEMM
// contracting that dim takes both operands by pure register reindexing:
//     frag[nt][ks] = pk16( acc2[2ks][nb], acc2[2ks+1][nb] )
// map pi(ks,i,g)=16*(2ks+(i>>2))+4g+(i&3). W1/W2 pre-permuted to pi-layout.
//
// Layout facts (cdna4 guide, measured m89/m91):
//   C/D: lane holds col=lane&15, rows 16mt+4(lane>>4)+j
//   A/B: row(col)=lane&15, kappa = 32ks+8(lane>>4)+i

typedef _Float16 half8 __attribute__((ext_vector_type(8)));
typedef __fp16 fp16x2 __attribute__((ext_vector_type(2)));
typedef float f4 __attribute__((ext_vector_type(4)));

#define MFMA16(a, b, c) __builtin_amdgcn_mfma_f32_16x16x32_f16((a), (b), (c), 0, 0, 0)

__global__ __launch_bounds__(256) void prep_weights(
    const float* __restrict__ Wq, const float* __restrict__ Wk,
    const float* __restrict__ Wv, const float* __restrict__ W1,
    const float* __restrict__ W2, _Float16* __restrict__ wsH) {
    int idx = blockIdx.x * 256 + threadIdx.x;  // 0..20479
    int m = idx >> 12, r = idx & 4095;
    const float* src = (m == 0) ? Wq : (m == 1) ? Wk : (m == 2) ? Wv
                        : (m == 3) ? W1 : W2;
    float v;
    if (m < 3) {
        v = src[r];  // natural row-major [e][d]
    } else {
        // pi-permuted: position (e, kappa) holds W[e][ d=16*(2ks+(i>>2))+4g+(i&3) ]
        int e = r >> 6, kp = r & 63;
        int ks = kp >> 5, gg = (kp >> 3) & 3, i = kp & 7;
        int d = 16 * (2 * ks + (i >> 2)) + 4 * gg + (i & 3);
        v = src[e * 64 + d];
    }
    wsH[idx] = (_Float16)v;
}

// Packed f32x4 + f32x4 -> half8 via v_cvt_pkrtz_f16_f32 (4 insts).
__device__ __forceinline__ half8 pk8(f4 a, f4 b) {
    union { half8 h; fp16x2 p[4]; } u;
    u.p[0] = __builtin_amdgcn_cvt_pkrtz(a[0], a[1]);
    u.p[1] = __builtin_amdgcn_cvt_pkrtz(a[2], a[3]);
    u.p[2] = __builtin_amdgcn_cvt_pkrtz(b[0], b[1]);
    u.p[3] = __builtin_amdgcn_cvt_pkrtz(b[2], b[3]);
    return u.h;
}

// Half-width GEMM into acc2[4][2]: output cols nt in {2h, 2h+1}.
// AEXPR uses (t, ks); BEXPR uses (nt, ks); CEXPR uses (mt, nb, nt).
#define GEMM_H(AEXPR, BEXPR, CEXPR)                                          \
    do {                                                                     \
        _Pragma("unroll")                                                    \
        for (int ks = 0; ks < 2; ++ks) {                                     \
            half8 afr[4], bfr[2];                                            \
            _Pragma("unroll")                                                \
            for (int t = 0; t < 4; ++t) afr[t] = (AEXPR);                    \
            _Pragma("unroll")                                                \
            for (int nb = 0; nb < 2; ++nb) {                                 \
                const int nt = 2 * h + nb; (void)nt;                         \
                bfr[nb] = (BEXPR);                                           \
            }                                                                \
            _Pragma("unroll")                                                \
            for (int mt = 0; mt < 4; ++mt)                                   \
                _Pragma("unroll")                                            \
                for (int nb = 0; nb < 2; ++nb) {                             \
                    const int nt = 2 * h + nb; (void)nt;                     \
                    acc2[mt][nb] = MFMA16(afr[mt], bfr[nb],                  \
                                          ks == 0 ? (CEXPR) : acc2[mt][nb]); \
                }                                                            \
        }                                                                    \
    } while (0)

// acc2 -> pi-layout frags for this half (dst[2h+nb][ks]).
#define MKFR_H(dst, RELU)                                                    \
    do {                                                                     \
        _Pragma("unroll")                                                    \
        for (int nb = 0; nb < 2; ++nb)                                       \
            _Pragma("unroll")                                                \
            for (int ks = 0; ks < 2; ++ks) {                                 \
                f4 a_ = acc2[2 * ks][nb], b_ = acc2[2 * ks + 1][nb];         \
                if (RELU) {                                                  \
                    _Pragma("unroll")                                        \
                    for (int j = 0; j < 4; ++j) {                            \
                        a_[j] = fmaxf(a_[j], 0.f);                           \
                        b_[j] = fmaxf(b_[j], 0.f);                           \
                    }                                                        \
                }                                                            \
                dst[2 * h + nb][ks] = pk8(a_, b_);                           \
            }                                                                \
    } while (0)

// Weight fragment from LDS: matrix widx, row-block RB (row = 16*RB+lo),
// kappa chunk (32ks+8g), XOR-swizzled by (lo&7)<<3 halves.
#define WFRAG(widx, RB) (*(const half8*)&wlds[(widx) * 4096 + (16 * (RB) + lo) * 64 + \
                                              ((32 * ks + 8 * g) ^ ((lo & 7) << 3))])

// x fragment from LDS (rows >= 60 -> zero; constant-folds for RB < 3).
#define XFRAG(RB) __extension__({                                            \
    int row_ = 16 * (RB) + lo;                                               \
    int rowc_ = row_ < 60 ? row_ : 48;                                       \
    half8 v_ = *(const half8*)&wlds[xbase + rowc_ * 64 +                     \
                                    ((32 * ks + 8 * g) ^ ((lo & 7) << 3))];  \
    if (row_ >= 60) { half8 z_ = {}; v_ = z_; }                              \
    v_; })

__global__ __launch_bounds__(512, 1) void fused_f16(
    const float* __restrict__ x, const _Float16* __restrict__ wH,
    const float* __restrict__ bq, const float* __restrict__ bk,
    const float* __restrict__ bv, const float* __restrict__ b1,
    const float* __restrict__ b2, const float* __restrict__ W3,
    const float* __restrict__ b3, float* __restrict__ out) {
    // 40 KB weights + 8 x-tiles (60x64 f16, swizzled) = 102400 B = 100 KB.
    __shared__ __align__(16) _Float16 wlds[51200];

    const int tid = threadIdx.x;
    const int l = tid & 63;           // lane
    const int w = tid >> 6;           // wave 0..7 (TWO sequential parts each)
    const int lo = l & 15, g = l >> 4;

    // ---- cooperative weight load global->LDS with write-side swizzle.
    #pragma unroll
    for (int rep = 0; rep < 5; ++rep) {
        int chunk = rep * 512 + tid;          // 0..2559
        int widx = chunk >> 9;
        int rem = chunk & 511;
        int row = rem >> 3, c = rem & 7;
        *(half8*)&wlds[widx * 4096 + row * 64 + ((c * 8) ^ ((row & 7) << 3))] =
            *(const half8*)&wH[widx * 4096 + row * 64 + c * 8];
    }
    __syncthreads();  // weights visible to all; waves independent afterwards

    const int part0 = blockIdx.x * 16 + w * 2;  // two consecutive parts
    const int xbase = 20480 + w * 3840;         // x tile reused per iteration

    #pragma unroll 1
    for (int it = 0; it < 2; ++it) {
        // Pin the back-edge: iteration it+1's loads may not hoist into it.
        __builtin_amdgcn_sched_barrier(0);

        const int part = part0 + it;
        const float* __restrict__ xp = x + (size_t)part * (60 * 64);

        // ---- stage this part's x into LDS (f16, swizzled). Same-wave
        // in-order LDS: this iteration's writes follow prior reads.
        #pragma unroll
        for (int m = 0; m < 8; ++m) {
            int chunk = m * 64 + l;           // 480 16B-chunks (60 rows x 8)
            if (chunk < 480) {
                int row = chunk >> 3, c = chunk & 7;
                const float* p = xp + row * 64 + c * 8;
                half8 hv = pk8(*(const f4*)p, *(const f4*)(p + 4));
                *(half8*)&wlds[xbase + row * 64 + ((c * 8) ^ ((row & 7) << 3))] = hv;
            }
        }

        const f4 zc = {0.f, 0.f, 0.f, 0.f};
        f4 acc2[4][2];
        f4 brow[4];
        half8 qf[4][2], kf[4][2], vf[4][2], pf[4][2], wtf[4][2], h1f[4][2];

        // ---- qT = Wq * xT + bq
        #pragma unroll
        for (int mt = 0; mt < 4; ++mt) brow[mt] = *(const f4*)&bq[16 * mt + 4 * g];
        #pragma unroll
        for (int h = 0; h < 2; ++h) {
            GEMM_H(WFRAG(0, t), XFRAG(nt), brow[mt]);
            MKFR_H(qf, false);
        }

        // ---- kT = Wk * xT + bk
        #pragma unroll
        for (int mt = 0; mt < 4; ++mt) brow[mt] = *(const f4*)&bk[16 * mt + 4 * g];
        #pragma unroll
        for (int h = 0; h < 2; ++h) {
            GEMM_H(WFRAG(1, t), XFRAG(nt), brow[mt]);
            MKFR_H(kf, false);
        }

        // ---- scoresT + softmax + P, per half (A = kf regs, B = qf regs)
        #pragma unroll
        for (int h = 0; h < 2; ++h) {
            GEMM_H(kf[t][ks], qf[nt][ks], zc);
            #pragma unroll
            for (int nb = 0; nb < 2; ++nb) {
                float sum = 0.f;
                #pragma unroll
                for (int mt = 0; mt < 4; ++mt)
                    #pragma unroll
                    for (int j = 0; j < 4; ++j) {
                        float e = (mt == 3 && g == 3)
                                      ? 0.f
                                      : exp2f(acc2[mt][nb][j] *
                                              0.1803368801111137f);
                        acc2[mt][nb][j] = e;
                        sum += e;
                    }
                sum += __shfl_xor(sum, 16);
                sum += __shfl_xor(sum, 32);
                float inv = 1.f / sum;
                #pragma unroll
                for (int mt = 0; mt < 4; ++mt)
                    #pragma unroll
                    for (int j = 0; j < 4; ++j) acc2[mt][nb][j] *= inv;
            }
            MKFR_H(pf, false);
        }
        // qf, kf dead here.

        // ---- v = x * WvT + bv (col-splat C-in), per half
        #pragma unroll
        for (int h = 0; h < 2; ++h) {
            float bc[2];
            #pragma unroll
            for (int nb = 0; nb < 2; ++nb) bc[nb] = bv[16 * (2 * h + nb) + lo];
            GEMM_H(XFRAG(t), WFRAG(2, nt),
                   ((f4){bc[nb], bc[nb], bc[nb], bc[nb]}));
            MKFR_H(vf, false);
        }

        // ---- weightedT = vT * P, per half (A = vf regs, B = pf regs)
        #pragma unroll
        for (int h = 0; h < 2; ++h) {
            GEMM_H(vf[t][ks], pf[nt][ks], zc);
            MKFR_H(wtf, false);
        }
        // vf, pf dead here.

        // ---- h1T = relu(W1 * weightedT + b1)   (W1 pi-permuted)
        #pragma unroll
        for (int mt = 0; mt < 4; ++mt) brow[mt] = *(const f4*)&b1[16 * mt + 4 * g];
        #pragma unroll
        for (int h = 0; h < 2; ++h) {
            GEMM_H(WFRAG(3, t), wtf[nt][ks], brow[mt]);
            MKFR_H(h1f, true);
        }

        // ---- h2T = relu(W2 * h1T + b2), head folded per half on f32 acc
        #pragma unroll
        for (int mt = 0; mt < 4; ++mt) brow[mt] = *(const f4*)&b2[16 * mt + 4 * g];
        f4 w3r[4];
        #pragma unroll
        for (int mt = 0; mt < 4; ++mt) w3r[mt] = *(const f4*)&W3[16 * mt + 4 * g];
        float b3v = b3[0];
        #pragma unroll
        for (int h = 0; h < 2; ++h) {
            GEMM_H(WFRAG(4, t), h1f[nt][ks], brow[mt]);
            #pragma unroll
            for (int nb = 0; nb < 2; ++nb) {
                float sres = 0.f;
                #pragma unroll
                for (int mt = 0; mt < 4; ++mt)
                    #pragma unroll
                    for (int j = 0; j < 4; ++j)
                        sres += fmaxf(acc2[mt][nb][j], 0.f) * w3r[mt][j];
                sres += __shfl_xor(sres, 16);
                sres += __shfl_xor(sres, 32);
                if (g == 0) {
                    int s = 16 * (2 * h + nb) + lo;
                    if (s < 60) out[(size_t)part * 60 + s] = sres + b3v;
                }
            }
        }
    }
}

extern "C" void kernel_launch(void* const* d_in, const int* in_sizes, int n_in,
                              void* d_out, int out_size, void* d_ws, size_t ws_size,
                              hipStream_t stream) {
    const float* x  = (const float*)d_in[0];
    const float* Wq = (const float*)d_in[1];
    const float* bq = (const float*)d_in[2];
    const float* Wk = (const float*)d_in[3];
    const float* bk = (const float*)d_in[4];
    const float* Wv = (const float*)d_in[5];
    const float* bv = (const float*)d_in[6];
    const float* W1 = (const float*)d_in[7];
    const float* b1 = (const float*)d_in[8];
    const float* W2 = (const float*)d_in[9];
    const float* b2 = (const float*)d_in[10];
    const float* W3 = (const float*)d_in[11];
    const float* b3 = (const float*)d_in[12];
    _Float16* wsH = (_Float16*)d_ws;  // 5 * 4096 halves = 40 KB

    prep_weights<<<80, 256, 0, stream>>>(Wq, Wk, Wv, W1, W2, wsH);
    // 640 WGs x 512 thr = 5120 waves; each wave runs 2 sequential parts
    // with the low-liveness R20 stage form (no A-preload -> no loop spill).
    fused_f16<<<640, 512, 0, stream>>>(x, wsH, bq, bk, bv, b1, b2, W3, b3,
                                       (float*)d_out);
}